// Round 1
// 1271.587 us; speedup vs baseline: 1.3373x; 1.3373x over previous
//
#include <hip/hip_runtime.h>

// ---------- types ----------
typedef __attribute__((ext_vector_type(8))) short bf16x8;   // 8 bf16 in 4 VGPRs
typedef __attribute__((ext_vector_type(4))) float f32x4;

// ---------- bf16 helpers (RNE, bit-level) ----------
__device__ __forceinline__ short f2bf(float f) {
    union { float f; unsigned u; } v; v.f = f;
    unsigned r = v.u + 0x7fffu + ((v.u >> 16) & 1u);
    return (short)(r >> 16);
}
__device__ __forceinline__ float bf2f(short s) {
    union { unsigned u; float f; } v; v.u = ((unsigned)(unsigned short)s) << 16;
    return v.f;
}
__device__ __forceinline__ unsigned pack2(float x, float y) {
    return (unsigned)(unsigned short)f2bf(x) | ((unsigned)(unsigned short)f2bf(y) << 16);
}
__device__ __forceinline__ uint4 pack8(float4 a, float4 b) {
    return make_uint4(pack2(a.x, a.y), pack2(a.z, a.w), pack2(b.x, b.y), pack2(b.z, b.w));
}
__device__ __forceinline__ float tanh_fast(float x) {
    float e = __expf(2.f * x);
    return 1.f - 2.f / (e + 1.f);
}

// async global -> LDS, 16B per lane (dest = wave-uniform base + lane*16)
__device__ __forceinline__ void gll16(const void* gp, void* lp) {
    __builtin_amdgcn_global_load_lds(
        (__attribute__((address_space(1))) void*)gp,
        (__attribute__((address_space(3))) void*)lp, 16, 0, 0);
}

// ---------- prep: fp32 [1024][1024] -> bf16 ----------
__global__ __launch_bounds__(256) void pack_w(const float* __restrict__ src,
                                              short* __restrict__ dst) {
    int idx = (blockIdx.x * 256 + threadIdx.x) * 8;
    float4 f0 = ((const float4*)(src + idx))[0];
    float4 f1 = ((const float4*)(src + idx))[1];
    *(uint4*)(dst + idx) = pack8(f0, f1);
}

__global__ void prep_b(const float* __restrict__ b_ih, const float* __restrict__ b_hh,
                       float* __restrict__ bsum) {
    int n = threadIdx.x;
    bsum[n] = b_ih[n] + b_hh[n];
}

// ---------- convert av fp32 [b][t][k] -> bf16 X[t*1024+b][k] (scan-row order) ----------
__global__ __launch_bounds__(256) void conv_av(const float* __restrict__ av,
                                               short* __restrict__ X) {
    size_t e = ((size_t)blockIdx.x * 256 + threadIdx.x) * 8;
    size_t row = e >> 10;                 // b*64 + t
    int k = (int)(e & 1023);
    int b = (int)(row >> 6), t = (int)(row & 63);
    float4 f0 = *(const float4*)(av + e);
    float4 f1 = *(const float4*)(av + e + 4);
    *(uint4*)(X + ((size_t)t * 1024 + b) * 1024 + k) = pack8(f0, f1);
}

// ---------- zgemm2: m97-structure bf16 GEMM ----------
// Z[r][n] = X[r][k] . Wih[n][k] + bsum[n];  M=65536, N=1024, K=1024
// 128x128 tile, BK=64, 256 thr (4 waves 2x2, wave tile 64x64)
// global_load_lds width-16 staging, linear LDS [128][64], 2 barriers/K-step
__global__ __launch_bounds__(256) void zgemm2(const short* __restrict__ X,
                                              const short* __restrict__ Wih,
                                              const float* __restrict__ bsum,
                                              short* __restrict__ Z) {
    __shared__ short smem[16384];         // 32KB: As[128][64] + Bs[128][64]; epilogue: C[128][128]
    short* As = smem;
    short* Bs = smem + 8192;

    const int tid = threadIdx.x, lane = tid & 63, wave = tid >> 6;
    const int wm = wave >> 1, wn = wave & 1;
    const int m0 = blockIdx.y * 128, n0 = blockIdx.x * 128;

    // staging: wave w, inst i covers tile rows w*32 + i*8 + (lane>>3), col-shorts (lane&7)*8
    const int srow = wave * 32 + (lane >> 3);
    const int scol = (lane & 7) * 8;
    const short* asrc = X   + (size_t)(m0 + srow) * 1024 + scol;
    const short* bsrc = Wih + (size_t)(n0 + srow) * 1024 + scol;
    char* aldst = (char*)As + wave * 4096;   // + i*1024B, lane*16B added by HW
    char* bldst = (char*)Bs + wave * 4096;

    f32x4 acc[4][4];
    #pragma unroll
    for (int i = 0; i < 4; i++)
        #pragma unroll
        for (int j = 0; j < 4; j++) acc[i][j] = (f32x4)0.0f;

    const int r = lane & 15, q = lane >> 4;
    const int koff = q * 8;

    for (int kt = 0; kt < 16; ++kt) {
        const int kbase = kt * 64;
        #pragma unroll
        for (int i = 0; i < 4; i++) {
            gll16(asrc + kbase + i * 8192, aldst + i * 1024);
            gll16(bsrc + kbase + i * 8192, bldst + i * 1024);
        }
        __syncthreads();   // drains vmcnt: tiles resident in LDS

        #pragma unroll
        for (int ks = 0; ks < 2; ++ks) {
            bf16x8 af[4], bfr[4];
            #pragma unroll
            for (int i = 0; i < 4; i++) {
                af[i]  = *(const bf16x8*)&As[(wm * 64 + i * 16 + r) * 64 + ks * 32 + koff];
                bfr[i] = *(const bf16x8*)&Bs[(wn * 64 + i * 16 + r) * 64 + ks * 32 + koff];
            }
            #pragma unroll
            for (int i = 0; i < 4; i++)
                #pragma unroll
                for (int j = 0; j < 4; j++)
                    acc[i][j] = __builtin_amdgcn_mfma_f32_16x16x32_bf16(af[i], bfr[j], acc[i][j], 0, 0, 0);
        }
        __syncthreads();   // all reads done before next stage overwrites
    }

    // ---- epilogue: bias + bf16 -> LDS (XOR-swizzled), then coalesced 16B stores ----
    short* Csh = smem;    // [128][128] shorts = 32KB
    #pragma unroll
    for (int j = 0; j < 4; j++) {
        int colc = wn * 64 + j * 16 + r;           // column within tile
        float bs = bsum[n0 + colc];
        int chunkc = colc >> 3, rem = colc & 7;
        #pragma unroll
        for (int i = 0; i < 4; i++) {
            int rowb = wm * 64 + i * 16 + q * 4;
            #pragma unroll
            for (int rr = 0; rr < 4; rr++) {
                int row = rowb + rr;
                int sc = ((chunkc ^ (row & 7)) << 3) | rem;
                Csh[row * 128 + sc] = f2bf(acc[i][j][rr] + bs);
            }
        }
    }
    __syncthreads();
    #pragma unroll
    for (int p = 0; p < 8; p++) {
        int row = p * 16 + (tid >> 4);
        int chunk = tid & 15;
        int rc = chunk ^ (row & 7);
        uint4 v = *(const uint4*)&Csh[row * 128 + rc * 8];
        *(uint4*)(Z + (size_t)(m0 + row) * 1024 + n0 + chunk * 8) = v;
    }
}

// ---------- fallback zgemm (previous verified kernel, used if ws too small) ----------
#define ZLDK 72   // padded K stride (elems)

__global__ __launch_bounds__(256) void zgemm(const float* __restrict__ av,
                                             const short* __restrict__ Wih,
                                             const float* __restrict__ bsum,
                                             short* __restrict__ Z) {
    __shared__ short As[128 * ZLDK];
    __shared__ short Bs[128 * ZLDK];

    const int tid = threadIdx.x, lane = tid & 63, wave = tid >> 6;
    const int wm = wave >> 1, wn = wave & 1;
    const int m0 = blockIdx.y * 128, n0 = blockIdx.x * 128;
    const int srow = tid >> 1, scol = (tid & 1) * 32;

    const int gr = m0 + srow;
    const int tt = gr >> 10, bb = gr & 1023;
    const float* asrc = av + ((size_t)bb * 64 + tt) * 1024 + scol;
    const short* bsrc = Wih + (size_t)(n0 + srow) * 1024 + scol;

    uint4 ra[4], rb[4];
    #pragma unroll
    for (int j = 0; j < 4; j++) {
        float4 f0 = *(const float4*)(asrc + 8 * j);
        float4 f1 = *(const float4*)(asrc + 8 * j + 4);
        ra[j] = pack8(f0, f1);
        rb[j] = *(const uint4*)(bsrc + 8 * j);
    }

    f32x4 acc[4][4];
    #pragma unroll
    for (int i = 0; i < 4; i++)
        #pragma unroll
        for (int j = 0; j < 4; j++) acc[i][j] = (f32x4)0.0f;

    const int r = lane & 15, q = lane >> 4;
    const int koff = q * 8;

    for (int kt = 0; kt < 16; ++kt) {
        #pragma unroll
        for (int j = 0; j < 4; j++) {
            *(uint4*)&As[srow * ZLDK + scol + 8 * j] = ra[j];
            *(uint4*)&Bs[srow * ZLDK + scol + 8 * j] = rb[j];
        }
        __syncthreads();

        if (kt < 15) {
            int k = (kt + 1) * 64;
            #pragma unroll
            for (int j = 0; j < 4; j++) {
                float4 f0 = *(const float4*)(asrc + k + 8 * j);
                float4 f1 = *(const float4*)(asrc + k + 8 * j + 4);
                ra[j] = pack8(f0, f1);
                rb[j] = *(const uint4*)(bsrc + k + 8 * j);
            }
        }

        #pragma unroll
        for (int ks = 0; ks < 2; ++ks) {
            bf16x8 af[4], bfr[4];
            #pragma unroll
            for (int i = 0; i < 4; i++) {
                af[i]  = *(const bf16x8*)&As[(wm * 64 + i * 16 + r) * ZLDK + ks * 32 + koff];
                bfr[i] = *(const bf16x8*)&Bs[(wn * 64 + i * 16 + r) * ZLDK + ks * 32 + koff];
            }
            #pragma unroll
            for (int i = 0; i < 4; i++)
                #pragma unroll
                for (int j = 0; j < 4; j++)
                    acc[i][j] = __builtin_amdgcn_mfma_f32_16x16x32_bf16(af[i], bfr[j], acc[i][j], 0, 0, 0);
        }
        __syncthreads();
    }

    #pragma unroll
    for (int j = 0; j < 4; j++) {
        int n = n0 + wn * 64 + j * 16 + r;
        float bs = bsum[n];
        #pragma unroll
        for (int i = 0; i < 4; i++) {
            int mb = m0 + wm * 64 + i * 16 + q * 4;
            #pragma unroll
            for (int rr = 0; rr < 4; rr++)
                Z[(size_t)(mb + rr) * 1024 + n] = f2bf(acc[i][j][rr] + bs);
        }
    }
}

// ---------- t=0: h1 = tanh(Z[0]) elementwise ----------
__global__ __launch_bounds__(256) void t0_kernel(const short* __restrict__ Z,
                                                 short* __restrict__ h) {
    int idx = (blockIdx.x * 256 + threadIdx.x) * 8;
    uint4 zv = *(const uint4*)(Z + idx);
    const unsigned* zp = (const unsigned*)&zv;
    uint4 out;
    unsigned* op = (unsigned*)&out;
    #pragma unroll
    for (int j = 0; j < 4; j++) {
        float lo = tanh_fast(bf2f((short)(zp[j] & 0xffffu)));
        float hi = tanh_fast(bf2f((short)(zp[j] >> 16)));
        op[j] = pack2(lo, hi);
    }
    *(uint4*)(h + idx) = out;
}

// ---------- RNN step t>=1: h' = tanh(h . W_hh^T + Z[t]) ----------
#define SLDK 136

__global__ __launch_bounds__(512) void step_kernel(const short* __restrict__ Whh,
                                                   const short* __restrict__ Z,
                                                   const short* __restrict__ h_in,
                                                   short* __restrict__ h_out, int t) {
    __shared__ short As[64 * SLDK];
    __shared__ short Bs[64 * SLDK];

    const int tid = threadIdx.x, lane = tid & 63, wave = tid >> 6;
    const int wm = wave >> 2, wn = wave & 3;
    const int m0 = blockIdx.y * 64, n0 = blockIdx.x * 64;
    const int srow = tid >> 3, scol = (tid & 7) * 16;

    const short* asrc = h_in + (size_t)(m0 + srow) * 1024 + scol;
    const short* bsrc = Whh + (size_t)(n0 + srow) * 1024 + scol;

    uint4 ra0 = *(const uint4*)asrc;
    uint4 ra1 = *(const uint4*)(asrc + 8);
    uint4 rb0 = *(const uint4*)bsrc;
    uint4 rb1 = *(const uint4*)(bsrc + 8);

    f32x4 acc[2];
    acc[0] = (f32x4)0.0f;
    acc[1] = (f32x4)0.0f;

    const int r = lane & 15, q = lane >> 4;
    const int arow = wm * 32 + r, brow = wn * 16 + r;
    const int koff = q * 8;

    for (int chunk = 0; chunk < 8; ++chunk) {
        *(uint4*)&As[srow * SLDK + scol]     = ra0;
        *(uint4*)&As[srow * SLDK + scol + 8] = ra1;
        *(uint4*)&Bs[srow * SLDK + scol]     = rb0;
        *(uint4*)&Bs[srow * SLDK + scol + 8] = rb1;
        __syncthreads();

        if (chunk < 7) {
            int k = (chunk + 1) * 128;
            ra0 = *(const uint4*)(asrc + k);
            ra1 = *(const uint4*)(asrc + k + 8);
            rb0 = *(const uint4*)(bsrc + k);
            rb1 = *(const uint4*)(bsrc + k + 8);
        }

        #pragma unroll
        for (int ks = 0; ks < 4; ++ks) {
            bf16x8 a0 = *(const bf16x8*)&As[arow * SLDK + ks * 32 + koff];
            bf16x8 a1 = *(const bf16x8*)&As[(arow + 16) * SLDK + ks * 32 + koff];
            bf16x8 b  = *(const bf16x8*)&Bs[brow * SLDK + ks * 32 + koff];
            acc[0] = __builtin_amdgcn_mfma_f32_16x16x32_bf16(a0, b, acc[0], 0, 0, 0);
            acc[1] = __builtin_amdgcn_mfma_f32_16x16x32_bf16(a1, b, acc[1], 0, 0, 0);
        }
        __syncthreads();
    }

    const short* zt = Z + ((size_t)t << 20);
    int n = n0 + wn * 16 + r;
    #pragma unroll
    for (int mi = 0; mi < 2; mi++) {
        int mb = m0 + wm * 32 + mi * 16 + q * 4;
        #pragma unroll
        for (int rr = 0; rr < 4; rr++) {
            float z = bf2f(zt[((size_t)(mb + rr) << 10) + n]);
            h_out[((size_t)(mb + rr) << 10) + n] = f2bf(tanh_fast(acc[mi][rr] + z));
        }
    }
}

// ---------- head: p[b] = sigmoid(h . W_out + b_out), wave-per-row ----------
__global__ __launch_bounds__(256) void head_kernel(const short* __restrict__ h,
                                                   const float* __restrict__ W_out,
                                                   const float* __restrict__ b_out,
                                                   float* __restrict__ p) {
    int b    = blockIdx.x * 4 + (threadIdx.x >> 6);
    int lane = threadIdx.x & 63;
    float s = 0.f;
    for (int k = lane; k < 1024; k += 64)
        s += bf2f(h[(size_t)b * 1024 + k]) * W_out[k];
    #pragma unroll
    for (int off = 32; off > 0; off >>= 1) s += __shfl_down(s, off);
    if (lane == 0) p[b] = 1.f / (1.f + __expf(-(s + b_out[0])));
}

// ---------- loss: BCE mean with torch-style log clamp at -100 ----------
__global__ __launch_bounds__(1024) void loss_kernel(const float* __restrict__ p,
                                                    const float* __restrict__ y,
                                                    float* __restrict__ loss) {
    __shared__ float red[1024];
    int b = threadIdx.x;
    float pv = p[b];
    float yb = (y[b] >= 1e-5f) ? 1.f : 0.f;
    float lp = fmaxf(logf(pv), -100.f);
    float l1 = fmaxf(log1pf(-pv), -100.f);
    red[b] = yb * lp + (1.f - yb) * l1;
    __syncthreads();
    for (int s = 512; s > 0; s >>= 1) {
        if (b < s) red[b] += red[b + s];
        __syncthreads();
    }
    if (b == 0) loss[0] = -red[0] / 1024.f;
}

// ---------- launch ----------
extern "C" void kernel_launch(void* const* d_in, const int* in_sizes, int n_in,
                              void* d_out, int out_size, void* d_ws, size_t ws_size,
                              hipStream_t stream) {
    const float* av    = (const float*)d_in[3];
    const float* y     = (const float*)d_in[4];
    const float* W_ih  = (const float*)d_in[5];
    const float* b_ih  = (const float*)d_in[6];
    const float* W_hh  = (const float*)d_in[7];
    const float* b_hh  = (const float*)d_in[8];
    const float* W_out = (const float*)d_in[9];
    const float* b_out = (const float*)d_in[10];
    float* out = (float*)d_out;                      // [0]=loss, [1..1024]=p

    char* ws = (char*)d_ws;
    short* Wih_bf = (short*)ws;                      // 2 MB
    short* Whh_bf = (short*)(ws + (2u << 20));       // 2 MB
    float* bsum   = (float*)(ws + (4u << 20));       // 4 KB
    short* hb0    = (short*)(ws + (5u << 20));       // 2 MB
    short* hb1    = (short*)(ws + (7u << 20));       // 2 MB
    short* Z      = (short*)(ws + (9u << 20));       // 128 MB: [64][1024][1024] bf16
    short* X      = (short*)(ws + (137u << 20));     // 128 MB: bf16 av, scan-row order

    pack_w<<<512, 256, 0, stream>>>(W_ih, Wih_bf);
    pack_w<<<512, 256, 0, stream>>>(W_hh, Whh_bf);
    prep_b<<<1, 1024, 0, stream>>>(b_ih, b_hh, bsum);

    if (ws_size >= ((size_t)266 << 20)) {
        conv_av<<<32768, 256, 0, stream>>>(av, X);
        zgemm2<<<dim3(8, 512), 256, 0, stream>>>(X, Wih_bf, bsum, Z);
    } else {
        zgemm<<<dim3(8, 512), 256, 0, stream>>>(av, Wih_bf, bsum, Z);
    }

    short* hbuf[2] = { hb0, hb1 };
    t0_kernel<<<512, 256, 0, stream>>>(Z, hb1);      // h_1 = tanh(Z[0])
    for (int t = 1; t < 64; ++t) {
        short* hin  = hbuf[t & 1];
        short* hout = hbuf[(t + 1) & 1];
        step_kernel<<<dim3(16, 16), 512, 0, stream>>>(Whh_bf, Z, hin, hout, t);
    }
    // t=63 writes hbuf[0]
    head_kernel<<<256, 256, 0, stream>>>(hb0, W_out, b_out, out + 1);
    loss_kernel<<<1, 1024, 0, stream>>>(out + 1, y, out);
}